// Round 3
// baseline (313.159 us; speedup 1.0000x reference)
//
#include <hip/hip_runtime.h>

// SolventAccessibility: scatter-reduce atoms into (BATCH,NCHAIN,SEQ,NALT) bins,
// then normalize per-bin by residue-type min/max.
//
// R3 = R2 with hipMemsetAsync replaced by a zeroing kernel (infra failed on R2;
// memset was the only new API surface). Design: NREP privatized accumulator
// replicas in d_ws (replica = blockIdx%NREP) to cut atomic line contention;
// reduce+normalize fused in the final kernel.

#define PADV   (-999)
#define BATCH  8
#define NCHAIN 2
#define SEQL   1024
#define NALT   3
#define NRES   20
#define NATOMS 2000000
#define GLY    7
#define NBINS  (BATCH * NCHAIN * SEQL * NALT)   // 49152
#define NREPMAX 8

// ---------------------------------------------------------------------------
// zero the replica region (grid-stride, float4)
// ---------------------------------------------------------------------------
__global__ void k_zero(float4* __restrict__ p, int n4) {
    int i = blockIdx.x * blockDim.x + threadIdx.x;
    int stride = gridDim.x * blockDim.x;
    for (; i < n4; i += stride) p[i] = make_float4(0.f, 0.f, 0.f, 0.f);
}

// ---------------------------------------------------------------------------
// init seq to PAD + detect `alternatives` layout (1-byte bool vs int32).
// int32 little-endian 0/1 has byte==0 at positions !=0 (mod 4); np.bool_
// layout has ~70% nonzero bytes everywhere (p(all 64 zero) ≈ 0.3^64).
// ---------------------------------------------------------------------------
__global__ void k_init_seq(int* __restrict__ seq,
                           int* __restrict__ flag,
                           const unsigned char* __restrict__ altBytes) {
    int i = blockIdx.x * blockDim.x + threadIdx.x;
    if (i < NBINS) seq[i] = PADV;
    if (blockIdx.x == 0 && threadIdx.x < 64) {
        unsigned char b = altBytes[threadIdx.x * 4 + 1];
        unsigned long long m = __ballot(b != 0);
        if (threadIdx.x == 0) *flag = (m != 0ULL) ? 1 : 0;
    }
}

// ---------------------------------------------------------------------------
// scatter into replicated accumulators. replica r occupies
// [r*2*NBINS, r*2*NBINS+NBINS) = MC, [+NBINS, +2*NBINS) = SC.
// ---------------------------------------------------------------------------
__global__ void k_scatter_rep(const float* __restrict__ contRat,   // [NATOMS][NALT]
                              const int* __restrict__ desc,        // [NATOMS][5]
                              const unsigned char* __restrict__ altB,
                              const int* __restrict__ altI,
                              const int* __restrict__ flag,
                              float* __restrict__ rep,
                              int nrep,
                              int* __restrict__ seq) {
    int a = blockIdx.x * blockDim.x + threadIdx.x;
    if (a >= NATOMS) return;

    float* mc = rep + (size_t)(blockIdx.x % nrep) * (2 * NBINS);
    float* sc = mc + NBINS;

    const int atname  = desc[a * 5 + 0];
    const int resnum  = desc[a * 5 + 1];
    const int chain   = desc[a * 5 + 2];
    const int batchI  = desc[a * 5 + 3];
    const int resname = desc[a * 5 + 4];

    const bool valid = (atname != PADV);
    const bool is_bb = (atname >= 0) && (atname <= 3);   // BACKBONE = {0,1,2,3}
    const int  base  = ((batchI * NCHAIN + chain) * SEQL + resnum) * NALT;

    const bool byteLayout = (*flag != 0);   // uniform scalar branch

    #pragma unroll
    for (int alt = 0; alt < NALT; ++alt) {
        bool altv;
        if (byteLayout) altv = (altB[a * NALT + alt] != 0);
        else            altv = (altI[a * NALT + alt] != 0);
        if (altv && valid) {
            const float c = contRat[a * NALT + alt];
            const int   f = base + alt;
            if (is_bb) {
                atomicAdd(&mc[f], c);
                seq[f] = resname;   // all writers to f share resid -> same resname
            } else {
                atomicAdd(&sc[f], c);
            }
        }
    }
}

// ---------------------------------------------------------------------------
// reduce replicas + normalize + clip -> d_out
// ---------------------------------------------------------------------------
__global__ void k_reduce_final(const float* __restrict__ rep, int nrep,
                               const int* __restrict__ seq,
                               float* __restrict__ out,     // [2*NBINS]
                               const float* __restrict__ mcmax,
                               const float* __restrict__ mcmin,
                               const float* __restrict__ scmax,
                               const float* __restrict__ scmin) {
    int i = blockIdx.x * blockDim.x + threadIdx.x;
    if (i >= NBINS) return;

    float m = 0.0f, v = 0.0f;
    for (int r = 0; r < nrep; ++r) {
        m += rep[(size_t)r * (2 * NBINS) + i];
        v += rep[(size_t)r * (2 * NBINS) + NBINS + i];
    }

    const int s = seq[i];
    if (s != PADV) {
        int idx = s < 0 ? 0 : (s > NRES - 1 ? NRES - 1 : s);
        m = (m - mcmin[idx]) / (mcmax[idx] - mcmin[idx]);
        if (s != GLY) v = (v - scmin[idx]) / (scmax[idx] - scmin[idx]);
        else          v = 0.0f;
    }
    out[i]         = fminf(fmaxf(m, 0.0f), 1.0f);
    out[NBINS + i] = fminf(fmaxf(v, 0.0f), 1.0f);
}

// ---------------------------------------------------------------------------
// Fallback (tiny ws): accumulate directly in d_out, finalize in place.
// ---------------------------------------------------------------------------
__global__ void k_init_flat(float* __restrict__ out, int* __restrict__ seq,
                            int* __restrict__ flag,
                            const unsigned char* __restrict__ altBytes) {
    int i = blockIdx.x * blockDim.x + threadIdx.x;
    if (i < NBINS) { out[i] = 0.0f; out[NBINS + i] = 0.0f; seq[i] = PADV; }
    if (blockIdx.x == 0 && threadIdx.x < 64) {
        unsigned char b = altBytes[threadIdx.x * 4 + 1];
        unsigned long long m = __ballot(b != 0);
        if (threadIdx.x == 0) *flag = (m != 0ULL) ? 1 : 0;
    }
}

__global__ void k_final_flat(float* __restrict__ mc, float* __restrict__ sc,
                             const int* __restrict__ seq,
                             const float* __restrict__ mcmax,
                             const float* __restrict__ mcmin,
                             const float* __restrict__ scmax,
                             const float* __restrict__ scmin) {
    int i = blockIdx.x * blockDim.x + threadIdx.x;
    if (i >= NBINS) return;
    const int s = seq[i];
    float m = mc[i], v = sc[i];
    if (s != PADV) {
        int idx = s < 0 ? 0 : (s > NRES - 1 ? NRES - 1 : s);
        m = (m - mcmin[idx]) / (mcmax[idx] - mcmin[idx]);
        if (s != GLY) v = (v - scmin[idx]) / (scmax[idx] - scmin[idx]);
        else          v = 0.0f;
    }
    mc[i] = fminf(fmaxf(m, 0.0f), 1.0f);
    sc[i] = fminf(fmaxf(v, 0.0f), 1.0f);
}

// ---------------------------------------------------------------------------
extern "C" void kernel_launch(void* const* d_in, const int* in_sizes, int n_in,
                              void* d_out, int out_size, void* d_ws, size_t ws_size,
                              hipStream_t stream) {
    const float* contRat = (const float*)d_in[0];
    const float* mcmax   = (const float*)d_in[1];
    const float* mcmin   = (const float*)d_in[2];
    const float* scmax   = (const float*)d_in[3];
    const float* scmin   = (const float*)d_in[4];
    const int*   desc    = (const int*)d_in[5];
    const void*  alts    = d_in[6];

    float* out = (float*)d_out;

    const size_t seqBytes = (size_t)NBINS * sizeof(int);
    const size_t repBytes = (size_t)2 * NBINS * sizeof(float);

    int nrep = 0;
    if (ws_size >= repBytes + seqBytes + 64) {
        nrep = (int)((ws_size - seqBytes - 64) / repBytes);
        if (nrep > NREPMAX) nrep = NREPMAX;
    }

    const int scatterBlocks = (NATOMS + 255) / 256;
    const int binBlocks     = (NBINS + 255) / 256;

    if (nrep >= 1) {
        float* rep  = (float*)d_ws;
        int*   seq  = (int*)((char*)d_ws + (size_t)nrep * repBytes);
        int*   flag = seq + NBINS;

        const int n4 = (int)((size_t)nrep * repBytes / sizeof(float4));
        k_zero<<<256, 256, 0, stream>>>((float4*)rep, n4);
        k_init_seq<<<binBlocks, 256, 0, stream>>>(seq, flag,
                                                  (const unsigned char*)alts);
        k_scatter_rep<<<scatterBlocks, 256, 0, stream>>>(
            contRat, desc,
            (const unsigned char*)alts, (const int*)alts, flag,
            rep, nrep, seq);
        k_reduce_final<<<binBlocks, 256, 0, stream>>>(
            rep, nrep, seq, out, mcmax, mcmin, scmax, scmin);
    } else {
        // ws too small for replicas: round-1 path
        int* seq  = (int*)d_ws;
        int* flag = seq + NBINS;
        k_init_flat<<<binBlocks, 256, 0, stream>>>(out, seq, flag,
                                                   (const unsigned char*)alts);
        k_scatter_rep<<<scatterBlocks, 256, 0, stream>>>(
            contRat, desc,
            (const unsigned char*)alts, (const int*)alts, flag,
            out, 1, seq);
        k_final_flat<<<binBlocks, 256, 0, stream>>>(
            out, out + NBINS, seq, mcmax, mcmin, scmax, scmin);
    }
}

// Round 4
// 310.886 us; speedup vs baseline: 1.0073x; 1.0073x over previous
//
#include <hip/hip_runtime.h>

// SolventAccessibility: scatter-reduce atoms into (BATCH,NCHAIN,SEQ,NALT) bins,
// then normalize per-bin by residue-type min/max.
//
// R4: R3 showed agent-scope atomics are memory-side on gfx950 (135 MB write
// traffic, 8x replication = zero effect). This round: WORKGROUP-scope relaxed
// atomics into per-XCD replicas keyed by the hardware XCC_ID. Workgroup scope
// keeps the RMW cached in the local XCD L2 (all workgroups behind the same L2
// serialize in that TCC -> atomicity holds); replica-per-XCC makes the
// non-coherent-L2 partition exact. Kernel-boundary acquire/release provides
// inter-kernel visibility.

#define PADV   (-999)
#define BATCH  8
#define NCHAIN 2
#define SEQL   1024
#define NALT   3
#define NRES   20
#define NATOMS 2000000
#define GLY    7
#define NBINS  (BATCH * NCHAIN * SEQL * NALT)   // 49152
#define NXCC   8

__device__ __forceinline__ int xcc_id() {
    unsigned v;
    asm volatile("s_getreg_b32 %0, hwreg(HW_REG_XCC_ID)" : "=s"(v));
    return (int)(v & 7u);
}

// ---------------------------------------------------------------------------
// zero the replica region (grid-stride, float4)
// ---------------------------------------------------------------------------
__global__ void k_zero(float4* __restrict__ p, int n4) {
    int i = blockIdx.x * blockDim.x + threadIdx.x;
    int stride = gridDim.x * blockDim.x;
    for (; i < n4; i += stride) p[i] = make_float4(0.f, 0.f, 0.f, 0.f);
}

// ---------------------------------------------------------------------------
// init seq to PAD + detect `alternatives` layout (1-byte bool vs int32).
// int32 little-endian 0/1 has byte==0 at positions !=0 (mod 4); np.bool_
// layout has ~70% nonzero bytes everywhere (p(all 64 zero) ~ 0.3^64).
// ---------------------------------------------------------------------------
__global__ void k_init_seq(int* __restrict__ seq,
                           int* __restrict__ flag,
                           const unsigned char* __restrict__ altBytes) {
    int i = blockIdx.x * blockDim.x + threadIdx.x;
    if (i < NBINS) seq[i] = PADV;
    if (blockIdx.x == 0 && threadIdx.x < 64) {
        unsigned char b = altBytes[threadIdx.x * 4 + 1];
        unsigned long long m = __ballot(b != 0);
        if (threadIdx.x == 0) *flag = (m != 0ULL) ? 1 : 0;
    }
}

// ---------------------------------------------------------------------------
// scatter with workgroup-scope (L2-local) atomics into the XCC's replica.
// replica r occupies [r*2*NBINS, +NBINS) = MC, [+NBINS, +2*NBINS) = SC.
// ---------------------------------------------------------------------------
__global__ void k_scatter_xcc(const float* __restrict__ contRat,   // [NATOMS][NALT]
                              const int* __restrict__ desc,        // [NATOMS][5]
                              const unsigned char* __restrict__ altB,
                              const int* __restrict__ altI,
                              const int* __restrict__ flag,
                              float* __restrict__ rep,
                              int* __restrict__ seq) {
    int a = blockIdx.x * blockDim.x + threadIdx.x;
    if (a >= NATOMS) return;

    // scalar (SGPR) replica base — exact XCD partition
    float* mc = rep + (size_t)xcc_id() * (2 * NBINS);
    float* sc = mc + NBINS;

    const int atname  = desc[a * 5 + 0];
    const int resnum  = desc[a * 5 + 1];
    const int chain   = desc[a * 5 + 2];
    const int batchI  = desc[a * 5 + 3];
    const int resname = desc[a * 5 + 4];

    const bool valid = (atname != PADV);
    const bool is_bb = (atname >= 0) && (atname <= 3);   // BACKBONE = {0,1,2,3}
    const int  base  = ((batchI * NCHAIN + chain) * SEQL + resnum) * NALT;

    const bool byteLayout = (*flag != 0);   // uniform scalar branch

    #pragma unroll
    for (int alt = 0; alt < NALT; ++alt) {
        bool altv;
        if (byteLayout) altv = (altB[a * NALT + alt] != 0);
        else            altv = (altI[a * NALT + alt] != 0);
        if (altv && valid) {
            const float c = contRat[a * NALT + alt];
            const int   f = base + alt;
            if (is_bb) {
                __hip_atomic_fetch_add(&mc[f], c, __ATOMIC_RELAXED,
                                       __HIP_MEMORY_SCOPE_WORKGROUP);
                seq[f] = resname;   // all writers to f share resid -> same resname
            } else {
                __hip_atomic_fetch_add(&sc[f], c, __ATOMIC_RELAXED,
                                       __HIP_MEMORY_SCOPE_WORKGROUP);
            }
        }
    }
}

// ---------------------------------------------------------------------------
// reduce 8 replicas + normalize + clip -> d_out
// ---------------------------------------------------------------------------
__global__ void k_reduce_final(const float* __restrict__ rep,
                               const int* __restrict__ seq,
                               float* __restrict__ out,     // [2*NBINS]
                               const float* __restrict__ mcmax,
                               const float* __restrict__ mcmin,
                               const float* __restrict__ scmax,
                               const float* __restrict__ scmin) {
    int i = blockIdx.x * blockDim.x + threadIdx.x;
    if (i >= NBINS) return;

    float m = 0.0f, v = 0.0f;
    #pragma unroll
    for (int r = 0; r < NXCC; ++r) {
        m += rep[(size_t)r * (2 * NBINS) + i];
        v += rep[(size_t)r * (2 * NBINS) + NBINS + i];
    }

    const int s = seq[i];
    if (s != PADV) {
        int idx = s < 0 ? 0 : (s > NRES - 1 ? NRES - 1 : s);
        m = (m - mcmin[idx]) / (mcmax[idx] - mcmin[idx]);
        if (s != GLY) v = (v - scmin[idx]) / (scmax[idx] - scmin[idx]);
        else          v = 0.0f;
    }
    out[i]         = fminf(fmaxf(m, 0.0f), 1.0f);
    out[NBINS + i] = fminf(fmaxf(v, 0.0f), 1.0f);
}

// ---------------------------------------------------------------------------
// Fallback (tiny ws): agent-scope atomics directly into d_out.
// ---------------------------------------------------------------------------
__global__ void k_init_flat(float* __restrict__ out, int* __restrict__ seq,
                            int* __restrict__ flag,
                            const unsigned char* __restrict__ altBytes) {
    int i = blockIdx.x * blockDim.x + threadIdx.x;
    if (i < NBINS) { out[i] = 0.0f; out[NBINS + i] = 0.0f; seq[i] = PADV; }
    if (blockIdx.x == 0 && threadIdx.x < 64) {
        unsigned char b = altBytes[threadIdx.x * 4 + 1];
        unsigned long long m = __ballot(b != 0);
        if (threadIdx.x == 0) *flag = (m != 0ULL) ? 1 : 0;
    }
}

__global__ void k_scatter_flat(const float* __restrict__ contRat,
                               const int* __restrict__ desc,
                               const unsigned char* __restrict__ altB,
                               const int* __restrict__ altI,
                               const int* __restrict__ flag,
                               float* __restrict__ mcArr,
                               float* __restrict__ scArr,
                               int* __restrict__ seq) {
    int a = blockIdx.x * blockDim.x + threadIdx.x;
    if (a >= NATOMS) return;
    const int atname  = desc[a * 5 + 0];
    const int resnum  = desc[a * 5 + 1];
    const int chain   = desc[a * 5 + 2];
    const int batchI  = desc[a * 5 + 3];
    const int resname = desc[a * 5 + 4];
    const bool valid = (atname != PADV);
    const bool is_bb = (atname >= 0) && (atname <= 3);
    const int  base  = ((batchI * NCHAIN + chain) * SEQL + resnum) * NALT;
    const bool byteLayout = (*flag != 0);
    #pragma unroll
    for (int alt = 0; alt < NALT; ++alt) {
        bool altv;
        if (byteLayout) altv = (altB[a * NALT + alt] != 0);
        else            altv = (altI[a * NALT + alt] != 0);
        if (altv && valid) {
            const float c = contRat[a * NALT + alt];
            const int   f = base + alt;
            if (is_bb) { atomicAdd(&mcArr[f], c); seq[f] = resname; }
            else       { atomicAdd(&scArr[f], c); }
        }
    }
}

__global__ void k_final_flat(float* __restrict__ mc, float* __restrict__ sc,
                             const int* __restrict__ seq,
                             const float* __restrict__ mcmax,
                             const float* __restrict__ mcmin,
                             const float* __restrict__ scmax,
                             const float* __restrict__ scmin) {
    int i = blockIdx.x * blockDim.x + threadIdx.x;
    if (i >= NBINS) return;
    const int s = seq[i];
    float m = mc[i], v = sc[i];
    if (s != PADV) {
        int idx = s < 0 ? 0 : (s > NRES - 1 ? NRES - 1 : s);
        m = (m - mcmin[idx]) / (mcmax[idx] - mcmin[idx]);
        if (s != GLY) v = (v - scmin[idx]) / (scmax[idx] - scmin[idx]);
        else          v = 0.0f;
    }
    mc[i] = fminf(fmaxf(m, 0.0f), 1.0f);
    sc[i] = fminf(fmaxf(v, 0.0f), 1.0f);
}

// ---------------------------------------------------------------------------
extern "C" void kernel_launch(void* const* d_in, const int* in_sizes, int n_in,
                              void* d_out, int out_size, void* d_ws, size_t ws_size,
                              hipStream_t stream) {
    const float* contRat = (const float*)d_in[0];
    const float* mcmax   = (const float*)d_in[1];
    const float* mcmin   = (const float*)d_in[2];
    const float* scmax   = (const float*)d_in[3];
    const float* scmin   = (const float*)d_in[4];
    const int*   desc    = (const int*)d_in[5];
    const void*  alts    = d_in[6];

    float* out = (float*)d_out;

    const size_t seqBytes = (size_t)NBINS * sizeof(int);
    const size_t repBytes = (size_t)2 * NBINS * sizeof(float);
    const size_t need     = (size_t)NXCC * repBytes + seqBytes + 64;

    const int scatterBlocks = (NATOMS + 255) / 256;
    const int binBlocks     = (NBINS + 255) / 256;

    if (ws_size >= need) {
        float* rep  = (float*)d_ws;
        int*   seq  = (int*)((char*)d_ws + (size_t)NXCC * repBytes);
        int*   flag = seq + NBINS;

        const int n4 = (int)((size_t)NXCC * repBytes / sizeof(float4));
        k_zero<<<256, 256, 0, stream>>>((float4*)rep, n4);
        k_init_seq<<<binBlocks, 256, 0, stream>>>(seq, flag,
                                                  (const unsigned char*)alts);
        k_scatter_xcc<<<scatterBlocks, 256, 0, stream>>>(
            contRat, desc,
            (const unsigned char*)alts, (const int*)alts, flag,
            rep, seq);
        k_reduce_final<<<binBlocks, 256, 0, stream>>>(
            rep, seq, out, mcmax, mcmin, scmax, scmin);
    } else {
        // ws too small for XCC replicas: agent-scope fallback
        int* seq  = (int*)d_ws;
        int* flag = seq + NBINS;
        k_init_flat<<<binBlocks, 256, 0, stream>>>(out, seq, flag,
                                                   (const unsigned char*)alts);
        k_scatter_flat<<<scatterBlocks, 256, 0, stream>>>(
            contRat, desc,
            (const unsigned char*)alts, (const int*)alts, flag,
            out, out + NBINS, seq);
        k_final_flat<<<binBlocks, 256, 0, stream>>>(
            out, out + NBINS, seq, mcmax, mcmin, scmax, scmin);
    }
}

// Round 5
// 267.078 us; speedup vs baseline: 1.1725x; 1.1640x over previous
//
#include <hip/hip_runtime.h>

// SolventAccessibility — R5: zero-global-atomic design.
// Evidence R1–R4: global fp atomics on gfx950 are memory-side at fixed
// per-op cost (135 MB write-through for 4.2M ops; scope/replication = no
// effect). So: dense per-plane LDS accumulation. 6 planes = alt{0,1,2} x
// {MC,SC}; each plane = 16384 residues x f32 = 64 KB LDS. Block (plane p,
// slice s) scans its atom slice, ds_add_f32 into the plane, flushes a dense
// partial. Reduce kernel sums partials + normalize + clip.

#define PADV   (-999)
#define BATCH  8
#define NCHAIN 2
#define SEQL   1024
#define NALT   3
#define NRES   20
#define NATOMS 2000000
#define GLY    7
#define NRESID (BATCH * NCHAIN * SEQL)       // 16384 residues
#define NBINS  (NRESID * NALT)               // 49152 output bins per tensor
#define NPLANE 6                             // alt(3) x side(2: 0=MC,1=SC)
#define SMAX   86

// ---------------------------------------------------------------------------
// init seq to PAD + detect `alternatives` layout (1-byte bool vs int32).
// int32 little-endian 0/1 has byte==0 at positions !=0 (mod 4); np.bool_
// layout has ~70% nonzero bytes (p(all 64 sampled zero) ~ 0.3^64).
// ---------------------------------------------------------------------------
__global__ void k_init_seq(int* __restrict__ seq,
                           int* __restrict__ flag,
                           const unsigned char* __restrict__ altBytes) {
    int i = blockIdx.x * blockDim.x + threadIdx.x;
    if (i < NBINS) seq[i] = PADV;
    if (blockIdx.x == 0 && threadIdx.x < 64) {
        unsigned char b = altBytes[threadIdx.x * 4 + 1];
        unsigned long long m = __ballot(b != 0);
        if (threadIdx.x == 0) *flag = (m != 0ULL) ? 1 : 0;
    }
}

// ---------------------------------------------------------------------------
// scan: block = (plane p, slice s). LDS-accumulate plane p over slice s.
// part layout: [NPLANE][S][NRESID] f32, written densely per block.
// ---------------------------------------------------------------------------
__global__ __launch_bounds__(512)
void k_scan(const float* __restrict__ contRat,     // [NATOMS][NALT]
            const int* __restrict__ desc,          // [NATOMS][5]
            const unsigned char* __restrict__ altB,
            const int* __restrict__ altI,
            const int* __restrict__ flag,
            float* __restrict__ part,
            int* __restrict__ seq,
            int S, int sliceSz) {
    __shared__ float acc[NRESID];                  // 64 KB

    const int p    = blockIdx.x % NPLANE;
    const int s    = blockIdx.x / NPLANE;
    const int alt  = p >> 1;
    const int side = p & 1;                        // 0 = MC (backbone), 1 = SC

    for (int j = threadIdx.x; j < NRESID; j += blockDim.x) acc[j] = 0.0f;
    __syncthreads();

    const bool byteLayout = (*flag != 0);
    const int start = s * sliceSz;
    int end = start + sliceSz;
    if (end > NATOMS) end = NATOMS;

    for (int i = start + (int)threadIdx.x; i < end; i += (int)blockDim.x) {
        int altv;
        if (byteLayout) altv = altB[i * NALT + alt];
        else            altv = altI[i * NALT + alt];
        if (!altv) continue;

        const int atname = desc[i * 5 + 0];
        if (atname == PADV) continue;
        const bool bb = ((unsigned)atname <= 3u);  // BACKBONE = {0,1,2,3}
        if ((side == 0) != bb) continue;

        const int resnum = desc[i * 5 + 1];
        const int chain  = desc[i * 5 + 2];
        const int batchI = desc[i * 5 + 3];
        const int r = (batchI * NCHAIN + chain) * SEQL + resnum;
        if ((unsigned)r >= (unsigned)NRESID) continue;

        atomicAdd(&acc[r], contRat[i * NALT + alt]);   // ds_add_f32, CU-local
        if (side == 0) seq[r * NALT + alt] = desc[i * 5 + 4];  // idempotent
    }
    __syncthreads();

    float* dst = part + ((size_t)p * S + s) * NRESID;
    for (int j = threadIdx.x; j < NRESID; j += blockDim.x) dst[j] = acc[j];
}

// ---------------------------------------------------------------------------
// reduce partials + normalize + clip -> d_out.
// thread t: r = t & 16383 (coalesced over partials), alt = t >> 14.
// ---------------------------------------------------------------------------
__global__ void k_reduce(const float* __restrict__ part, int S,
                         const int* __restrict__ seq,
                         float* __restrict__ out,      // [2*NBINS]
                         const float* __restrict__ mcmax,
                         const float* __restrict__ mcmin,
                         const float* __restrict__ scmax,
                         const float* __restrict__ scmin) {
    int t = blockIdx.x * blockDim.x + threadIdx.x;
    if (t >= NBINS) return;
    const int r   = t & (NRESID - 1);
    const int alt = t >> 14;

    const float* pm = part + ((size_t)(alt * 2 + 0) * S) * NRESID + r;
    const float* pv = part + ((size_t)(alt * 2 + 1) * S) * NRESID + r;
    float m = 0.0f, v = 0.0f;
    for (int s2 = 0; s2 < S; ++s2) {
        m += pm[(size_t)s2 * NRESID];
        v += pv[(size_t)s2 * NRESID];
    }

    const int f  = r * NALT + alt;
    const int sq = seq[f];
    if (sq != PADV) {
        int idx = sq < 0 ? 0 : (sq > NRES - 1 ? NRES - 1 : sq);
        m = (m - mcmin[idx]) / (mcmax[idx] - mcmin[idx]);
        if (sq != GLY) v = (v - scmin[idx]) / (scmax[idx] - scmin[idx]);
        else           v = 0.0f;
    }
    out[f]         = fminf(fmaxf(m, 0.0f), 1.0f);
    out[NBINS + f] = fminf(fmaxf(v, 0.0f), 1.0f);
}

// ---------------------------------------------------------------------------
// Fallback (tiny ws): R1 flat-atomic path.
// ---------------------------------------------------------------------------
__global__ void k_init_flat(float* __restrict__ out, int* __restrict__ seq,
                            int* __restrict__ flag,
                            const unsigned char* __restrict__ altBytes) {
    int i = blockIdx.x * blockDim.x + threadIdx.x;
    if (i < NBINS) { out[i] = 0.0f; out[NBINS + i] = 0.0f; seq[i] = PADV; }
    if (blockIdx.x == 0 && threadIdx.x < 64) {
        unsigned char b = altBytes[threadIdx.x * 4 + 1];
        unsigned long long m = __ballot(b != 0);
        if (threadIdx.x == 0) *flag = (m != 0ULL) ? 1 : 0;
    }
}

__global__ void k_scatter_flat(const float* __restrict__ contRat,
                               const int* __restrict__ desc,
                               const unsigned char* __restrict__ altB,
                               const int* __restrict__ altI,
                               const int* __restrict__ flag,
                               float* __restrict__ mcArr,
                               float* __restrict__ scArr,
                               int* __restrict__ seq) {
    int a = blockIdx.x * blockDim.x + threadIdx.x;
    if (a >= NATOMS) return;
    const int atname  = desc[a * 5 + 0];
    const int resnum  = desc[a * 5 + 1];
    const int chain   = desc[a * 5 + 2];
    const int batchI  = desc[a * 5 + 3];
    const int resname = desc[a * 5 + 4];
    const bool valid = (atname != PADV);
    const bool is_bb = (atname >= 0) && (atname <= 3);
    const int  base  = ((batchI * NCHAIN + chain) * SEQL + resnum) * NALT;
    const bool byteLayout = (*flag != 0);
    #pragma unroll
    for (int alt = 0; alt < NALT; ++alt) {
        bool altv;
        if (byteLayout) altv = (altB[a * NALT + alt] != 0);
        else            altv = (altI[a * NALT + alt] != 0);
        if (altv && valid) {
            const float c = contRat[a * NALT + alt];
            const int   f = base + alt;
            if (is_bb) { atomicAdd(&mcArr[f], c); seq[f] = resname; }
            else       { atomicAdd(&scArr[f], c); }
        }
    }
}

__global__ void k_final_flat(float* __restrict__ mc, float* __restrict__ sc,
                             const int* __restrict__ seq,
                             const float* __restrict__ mcmax,
                             const float* __restrict__ mcmin,
                             const float* __restrict__ scmax,
                             const float* __restrict__ scmin) {
    int i = blockIdx.x * blockDim.x + threadIdx.x;
    if (i >= NBINS) return;
    const int s = seq[i];
    float m = mc[i], v = sc[i];
    if (s != PADV) {
        int idx = s < 0 ? 0 : (s > NRES - 1 ? NRES - 1 : s);
        m = (m - mcmin[idx]) / (mcmax[idx] - mcmin[idx]);
        if (s != GLY) v = (v - scmin[idx]) / (scmax[idx] - scmin[idx]);
        else          v = 0.0f;
    }
    mc[i] = fminf(fmaxf(m, 0.0f), 1.0f);
    sc[i] = fminf(fmaxf(v, 0.0f), 1.0f);
}

// ---------------------------------------------------------------------------
extern "C" void kernel_launch(void* const* d_in, const int* in_sizes, int n_in,
                              void* d_out, int out_size, void* d_ws, size_t ws_size,
                              hipStream_t stream) {
    const float* contRat = (const float*)d_in[0];
    const float* mcmax   = (const float*)d_in[1];
    const float* mcmin   = (const float*)d_in[2];
    const float* scmax   = (const float*)d_in[3];
    const float* scmin   = (const float*)d_in[4];
    const int*   desc    = (const int*)d_in[5];
    const void*  alts    = d_in[6];

    float* out = (float*)d_out;
    const size_t seqBytes = (size_t)NBINS * sizeof(int);

    // How many slices fit in the workspace?
    int S = 0;
    if (ws_size > seqBytes + 64) {
        size_t availF = (ws_size - seqBytes - 64) / sizeof(float);
        size_t s = availF / ((size_t)NPLANE * NRESID);
        S = (s > SMAX) ? SMAX : (int)s;
    }

    const int binBlocks = (NBINS + 255) / 256;

    if (S >= 6) {
        float* part = (float*)d_ws;
        int*   seq  = (int*)((char*)d_ws +
                             (size_t)NPLANE * S * NRESID * sizeof(float));
        int*   flag = seq + NBINS;

        const int sliceSz = (NATOMS + S - 1) / S;

        k_init_seq<<<binBlocks, 256, 0, stream>>>(seq, flag,
                                                  (const unsigned char*)alts);
        k_scan<<<NPLANE * S, 512, 0, stream>>>(
            contRat, desc,
            (const unsigned char*)alts, (const int*)alts, flag,
            part, seq, S, sliceSz);
        k_reduce<<<binBlocks, 256, 0, stream>>>(
            part, S, seq, out, mcmax, mcmin, scmax, scmin);
    } else {
        // ws too small for the plane design: flat agent-scope atomic path
        int* seq  = (int*)d_ws;
        int* flag = seq + NBINS;
        k_init_flat<<<binBlocks, 256, 0, stream>>>(out, seq, flag,
                                                   (const unsigned char*)alts);
        k_scatter_flat<<<(NATOMS + 255) / 256, 256, 0, stream>>>(
            contRat, desc,
            (const unsigned char*)alts, (const int*)alts, flag,
            out, out + NBINS, seq);
        k_final_flat<<<binBlocks, 256, 0, stream>>>(
            out, out + NBINS, seq, mcmax, mcmin, scmax, scmin);
    }
}

// Round 6
// 197.564 us; speedup vs baseline: 1.5851x; 1.3519x over previous
//
#include <hip/hip_runtime.h>

// SolventAccessibility — R6: pack-then-scan, zero global atomics.
// R5 evidence: k_scan was fetch-bound (241 MB = 6 plane-passes x 40 MB desc).
// R6: (1) pack desc+alternatives into 4 B/atom once; (2) scan with 8 residue
// chunks x 6 planes in 48 KB LDS (16 waves/CU), reading 4 atoms per uint4;
// (3) reduce partials + normalize. Global fp atomics remain zero (R1-R4:
// memory-side, ~32 B/op, scope-independent).

#define PADV   (-999)
#define BATCH  8
#define NCHAIN 2
#define SEQL   1024
#define NALT   3
#define NRES   20
#define NATOMS 2000000
#define GLY    7
#define NRESID (BATCH * NCHAIN * SEQL)       // 16384 residues
#define NBINS  (NRESID * NALT)               // 49152 bins per output tensor
#define NCHUNK 8                             // residue chunks
#define CHSZ   (NRESID / NCHUNK)             // 2048 residues/chunk
#define SMAXSL 32                            // max atom slices (grid = 8*S)

// pack word: r[13:0] | resname[18:14] | bb[19] | altmask[22:20]
#define PK_R(w)    ((int)((w) & 16383u))
#define PK_RES(w)  ((int)(((w) >> 14) & 31u))
#define PK_BB(w)   (((w) >> 19) & 1u)
#define PK_AM(w)   ((w) >> 20)

// ---------------------------------------------------------------------------
__global__ void k_init_seq(int* __restrict__ seq) {
    int i = blockIdx.x * blockDim.x + threadIdx.x;
    if (i < NBINS) seq[i] = PADV;
}

// ---------------------------------------------------------------------------
// pack: 1 atom/thread. Detects alternatives layout per-wave:
// int32 0/1 little-endian has byte==0 at offsets !=0 (mod 4); np.bool_ is
// ~70% nonzero there (P(all 64 samples zero) ~ 0.3^64).
// ---------------------------------------------------------------------------
__global__ __launch_bounds__(512)
void k_pack(const int* __restrict__ desc,            // [NATOMS][5]
            const unsigned char* __restrict__ altB,
            const int* __restrict__ altI,
            unsigned* __restrict__ pack,
            int* __restrict__ seq) {
    const unsigned char probe = altB[(threadIdx.x & 63) * 4 + 1];
    const bool byteLayout = (__ballot(probe != 0) != 0ULL);

    const int i = blockIdx.x * blockDim.x + threadIdx.x;
    if (i >= NATOMS) return;

    const int atname  = desc[i * 5 + 0];
    const int resnum  = desc[i * 5 + 1];
    const int chain   = desc[i * 5 + 2];
    const int batchI  = desc[i * 5 + 3];
    const int resname = desc[i * 5 + 4] & 31;

    const bool valid = (atname != PADV);
    const bool bb    = ((unsigned)atname <= 3u);     // BACKBONE = {0,1,2,3}
    const int  r     = (batchI * NCHAIN + chain) * SEQL + resnum;
    const bool rOK   = ((unsigned)r < (unsigned)NRESID);

    unsigned am = 0;
    if (valid && rOK) {
        if (byteLayout) {
            am = (altB[i * 3 + 0] ? 1u : 0u) | (altB[i * 3 + 1] ? 2u : 0u)
               | (altB[i * 3 + 2] ? 4u : 0u);
        } else {
            am = (altI[i * 3 + 0] ? 1u : 0u) | (altI[i * 3 + 1] ? 2u : 0u)
               | (altI[i * 3 + 2] ? 4u : 0u);
        }
    }

    const unsigned rr = rOK ? (unsigned)r : 0u;
    pack[i] = rr | ((unsigned)resname << 14) | ((bb ? 1u : 0u) << 19) | (am << 20);

    if (bb && am) {                                   // idempotent seq stores
        if (am & 1) seq[r * 3 + 0] = resname;
        if (am & 2) seq[r * 3 + 1] = resname;
        if (am & 4) seq[r * 3 + 2] = resname;
    }
}

// ---------------------------------------------------------------------------
// scan: block = (chunk c = blockIdx%8, slice s = blockIdx/8).
// LDS: 6 planes x 2048 residues = 48 KB. part layout: [S][6][NRESID].
// ---------------------------------------------------------------------------
__global__ __launch_bounds__(1024)
void k_scan(const float* __restrict__ contRat,       // [NATOMS][NALT]
            const unsigned* __restrict__ pack,
            float* __restrict__ part,
            int S, int sliceSz) {
    __shared__ float acc[6 * CHSZ];                  // 48 KB

    const int c = blockIdx.x & (NCHUNK - 1);
    const int s = blockIdx.x >> 3;

    for (int j = threadIdx.x; j < 6 * CHSZ; j += blockDim.x) acc[j] = 0.0f;
    __syncthreads();

    const int start = s * sliceSz;
    int end = start + sliceSz;
    if (end > NATOMS) end = NATOMS;

    int i = start + (int)threadIdx.x * 4;
    const int step = (int)blockDim.x * 4;

    #define PROCESS(w, idx)                                                   \
        do {                                                                  \
            const unsigned am_ = PK_AM(w);                                    \
            if (am_) {                                                        \
                const int r_ = PK_R(w);                                       \
                if ((r_ >> 11) == c) {                                        \
                    const int lr_ = r_ & (CHSZ - 1);                          \
                    const int pb_ = (PK_BB(w) ? 0 : 3) * CHSZ + lr_;          \
                    const float* cr_ = contRat + (size_t)(idx) * 3;           \
                    if (am_ & 1) atomicAdd(&acc[pb_ + 0 * CHSZ], cr_[0]);     \
                    if (am_ & 2) atomicAdd(&acc[pb_ + 1 * CHSZ], cr_[1]);     \
                    if (am_ & 4) atomicAdd(&acc[pb_ + 2 * CHSZ], cr_[2]);     \
                }                                                             \
            }                                                                 \
        } while (0)

    for (; i + 3 < end; i += step) {
        const uint4 w4 = *(const uint4*)(pack + i);
        PROCESS(w4.x, i);
        PROCESS(w4.y, i + 1);
        PROCESS(w4.z, i + 2);
        PROCESS(w4.w, i + 3);
    }
    for (int k = i; k < end && k < i + 4; ++k) PROCESS(pack[k], k);
    #undef PROCESS

    __syncthreads();

    // flush: part[s][plane][c*CHSZ + j]
    for (int t = threadIdx.x; t < 6 * CHSZ; t += blockDim.x) {
        const int plane = t >> 11;
        const int j     = t & (CHSZ - 1);
        part[((size_t)s * 6 + plane) * NRESID + c * CHSZ + j] = acc[t];
    }
}

// ---------------------------------------------------------------------------
// reduce partials + normalize + clip -> d_out. plane MC = alt, SC = 3+alt.
// ---------------------------------------------------------------------------
__global__ void k_reduce(const float* __restrict__ part, int S,
                         const int* __restrict__ seq,
                         float* __restrict__ out,      // [2*NBINS]
                         const float* __restrict__ mcmax,
                         const float* __restrict__ mcmin,
                         const float* __restrict__ scmax,
                         const float* __restrict__ scmin) {
    int t = blockIdx.x * blockDim.x + threadIdx.x;
    if (t >= NBINS) return;
    const int r   = t & (NRESID - 1);
    const int alt = t >> 14;

    float m = 0.0f, v = 0.0f;
    for (int s2 = 0; s2 < S; ++s2) {
        m += part[((size_t)s2 * 6 + alt) * NRESID + r];
        v += part[((size_t)s2 * 6 + 3 + alt) * NRESID + r];
    }

    const int f  = r * NALT + alt;
    const int sq = seq[f];
    if (sq != PADV) {
        int idx = sq < 0 ? 0 : (sq > NRES - 1 ? NRES - 1 : sq);
        m = (m - mcmin[idx]) / (mcmax[idx] - mcmin[idx]);
        if (sq != GLY) v = (v - scmin[idx]) / (scmax[idx] - scmin[idx]);
        else           v = 0.0f;
    }
    out[f]         = fminf(fmaxf(m, 0.0f), 1.0f);
    out[NBINS + f] = fminf(fmaxf(v, 0.0f), 1.0f);
}

// ---------------------------------------------------------------------------
// Fallback (tiny ws): flat agent-scope atomics (proven R1).
// ---------------------------------------------------------------------------
__global__ void k_init_flat(float* __restrict__ out, int* __restrict__ seq,
                            int* __restrict__ flag,
                            const unsigned char* __restrict__ altBytes) {
    int i = blockIdx.x * blockDim.x + threadIdx.x;
    if (i < NBINS) { out[i] = 0.0f; out[NBINS + i] = 0.0f; seq[i] = PADV; }
    if (blockIdx.x == 0 && threadIdx.x < 64) {
        unsigned char b = altBytes[threadIdx.x * 4 + 1];
        unsigned long long m = __ballot(b != 0);
        if (threadIdx.x == 0) *flag = (m != 0ULL) ? 1 : 0;
    }
}

__global__ void k_scatter_flat(const float* __restrict__ contRat,
                               const int* __restrict__ desc,
                               const unsigned char* __restrict__ altB,
                               const int* __restrict__ altI,
                               const int* __restrict__ flag,
                               float* __restrict__ mcArr,
                               float* __restrict__ scArr,
                               int* __restrict__ seq) {
    int a = blockIdx.x * blockDim.x + threadIdx.x;
    if (a >= NATOMS) return;
    const int atname  = desc[a * 5 + 0];
    const int resnum  = desc[a * 5 + 1];
    const int chain   = desc[a * 5 + 2];
    const int batchI  = desc[a * 5 + 3];
    const int resname = desc[a * 5 + 4];
    const bool valid = (atname != PADV);
    const bool is_bb = (atname >= 0) && (atname <= 3);
    const int  base  = ((batchI * NCHAIN + chain) * SEQL + resnum) * NALT;
    const bool byteLayout = (*flag != 0);
    #pragma unroll
    for (int alt = 0; alt < NALT; ++alt) {
        bool altv;
        if (byteLayout) altv = (altB[a * NALT + alt] != 0);
        else            altv = (altI[a * NALT + alt] != 0);
        if (altv && valid) {
            const float c = contRat[a * NALT + alt];
            const int   f = base + alt;
            if (is_bb) { atomicAdd(&mcArr[f], c); seq[f] = resname; }
            else       { atomicAdd(&scArr[f], c); }
        }
    }
}

__global__ void k_final_flat(float* __restrict__ mc, float* __restrict__ sc,
                             const int* __restrict__ seq,
                             const float* __restrict__ mcmax,
                             const float* __restrict__ mcmin,
                             const float* __restrict__ scmax,
                             const float* __restrict__ scmin) {
    int i = blockIdx.x * blockDim.x + threadIdx.x;
    if (i >= NBINS) return;
    const int s = seq[i];
    float m = mc[i], v = sc[i];
    if (s != PADV) {
        int idx = s < 0 ? 0 : (s > NRES - 1 ? NRES - 1 : s);
        m = (m - mcmin[idx]) / (mcmax[idx] - mcmin[idx]);
        if (s != GLY) v = (v - scmin[idx]) / (scmax[idx] - scmin[idx]);
        else          v = 0.0f;
    }
    mc[i] = fminf(fmaxf(m, 0.0f), 1.0f);
    sc[i] = fminf(fmaxf(v, 0.0f), 1.0f);
}

// ---------------------------------------------------------------------------
extern "C" void kernel_launch(void* const* d_in, const int* in_sizes, int n_in,
                              void* d_out, int out_size, void* d_ws, size_t ws_size,
                              hipStream_t stream) {
    const float* contRat = (const float*)d_in[0];
    const float* mcmax   = (const float*)d_in[1];
    const float* mcmin   = (const float*)d_in[2];
    const float* scmax   = (const float*)d_in[3];
    const float* scmin   = (const float*)d_in[4];
    const int*   desc    = (const int*)d_in[5];
    const void*  alts    = d_in[6];

    float* out = (float*)d_out;

    const size_t packBytes  = (size_t)NATOMS * sizeof(unsigned);   // 8 MB
    const size_t seqBytes   = (size_t)NBINS * sizeof(int);         // 192 KB
    const size_t sliceBytes = (size_t)6 * NRESID * sizeof(float);  // 384 KB

    int S = 0;
    if (ws_size > packBytes + seqBytes + 64) {
        size_t s = (ws_size - packBytes - seqBytes - 64) / sliceBytes;
        S = (s > SMAXSL) ? SMAXSL : (int)s;
    }

    const int binBlocks = (NBINS + 255) / 256;

    if (S >= 2) {
        unsigned* pack = (unsigned*)d_ws;
        float*    part = (float*)((char*)d_ws + packBytes);
        int*      seq  = (int*)((char*)d_ws + packBytes + (size_t)S * sliceBytes);

        int sliceSz = (NATOMS + S - 1) / S;
        sliceSz = (sliceSz + 3) & ~3;                 // keep uint4 alignment

        k_init_seq<<<binBlocks, 256, 0, stream>>>(seq);
        k_pack<<<(NATOMS + 511) / 512, 512, 0, stream>>>(
            desc, (const unsigned char*)alts, (const int*)alts, pack, seq);
        k_scan<<<NCHUNK * S, 1024, 0, stream>>>(contRat, pack, part, S, sliceSz);
        k_reduce<<<binBlocks, 256, 0, stream>>>(
            part, S, seq, out, mcmax, mcmin, scmax, scmin);
    } else {
        // ws too small: flat agent-scope atomic path
        int* seq  = (int*)d_ws;
        int* flag = seq + NBINS;
        k_init_flat<<<binBlocks, 256, 0, stream>>>(out, seq, flag,
                                                   (const unsigned char*)alts);
        k_scatter_flat<<<(NATOMS + 255) / 256, 256, 0, stream>>>(
            contRat, desc,
            (const unsigned char*)alts, (const int*)alts, flag,
            out, out + NBINS, seq);
        k_final_flat<<<binBlocks, 256, 0, stream>>>(
            out, out + NBINS, seq, mcmax, mcmin, scmax, scmin);
    }
}

// Round 7
// 181.708 us; speedup vs baseline: 1.7234x; 1.0873x over previous
//
#include <hip/hip_runtime.h>

// SolventAccessibility — R7: pack-then-scan, zero global atomics.
// R6 counters: k_scan latency-bound at 1 block/CU (grid 256, occ 41%,
// VALUBusy 9%). R7: S up to 64 (grid 512 = 2 blocks/CU = 32 waves, 100% occ),
// k_init_seq deleted (reduce treats seq<0 as no-res; poison/zero both safe),
// k_pack vectorized 4 atoms/thread.

#define PADV   (-999)
#define BATCH  8
#define NCHAIN 2
#define SEQL   1024
#define NALT   3
#define NRES   20
#define NATOMS 2000000
#define GLY    7
#define NRESID (BATCH * NCHAIN * SEQL)       // 16384 residues
#define NBINS  (NRESID * NALT)               // 49152 bins per output tensor
#define NCHUNK 8                             // residue chunks
#define CHSZ   (NRESID / NCHUNK)             // 2048 residues/chunk
#define SMAXSL 64                            // max atom slices (grid = 8*S)

// pack word: r[13:0] | resname[18:14] | bb[19] | altmask[22:20]
#define PK_R(w)    ((int)((w) & 16383u))
#define PK_BB(w)   (((w) >> 19) & 1u)
#define PK_AM(w)   ((w) >> 20)

// ---------------------------------------------------------------------------
// pack: 4 atoms/thread, vectorized. Per-wave alternatives-layout detection:
// int32 0/1 little-endian has byte==0 at offsets !=0 (mod 4); np.bool_ is
// ~70% nonzero there (P(all 64 samples zero) ~ 0.3^64).
// ---------------------------------------------------------------------------
__global__ __launch_bounds__(256)
void k_pack(const int* __restrict__ desc,            // [NATOMS][5]
            const unsigned char* __restrict__ altB,
            const int* __restrict__ altI,
            unsigned* __restrict__ pack,
            int* __restrict__ seq) {
    const unsigned char probe = altB[(threadIdx.x & 63) * 4 + 1];
    const bool byteLayout = (__ballot(probe != 0) != 0ULL);

    const int t  = blockIdx.x * blockDim.x + threadIdx.x;
    const int a0 = t * 4;
    if (a0 >= NATOMS) return;

    // 4 desc rows = 20 ints = 5 aligned int4 loads
    const int4* d4 = (const int4*)(desc + (size_t)a0 * 5);
    int4 q0 = d4[0], q1 = d4[1], q2 = d4[2], q3 = d4[3], q4 = d4[4];
    // rows: atom0 = {q0.x..q0.w, q1.x}, atom1 = {q1.y..q2.y}, ...
    int an[4], rn[4], ch[4], bi[4], rs[4];
    an[0]=q0.x; rn[0]=q0.y; ch[0]=q0.z; bi[0]=q0.w; rs[0]=q1.x;
    an[1]=q1.y; rn[1]=q1.z; ch[1]=q1.w; bi[1]=q2.x; rs[1]=q2.y;
    an[2]=q2.z; rn[2]=q2.w; ch[2]=q3.x; bi[2]=q3.y; rs[2]=q3.z;
    an[3]=q3.w; rn[3]=q4.x; ch[3]=q4.y; bi[3]=q4.z; rs[3]=q4.w;

    // alternatives for 4 atoms (12 flags)
    unsigned am[4];
    if (byteLayout) {
        const unsigned* b3 = (const unsigned*)(altB + (size_t)a0 * 3);  // 12 B
        unsigned w0 = b3[0], w1 = b3[1], w2 = b3[2];
        unsigned char f[12];
        f[0]=w0; f[1]=w0>>8; f[2]=w0>>16; f[3]=w0>>24;
        f[4]=w1; f[5]=w1>>8; f[6]=w1>>16; f[7]=w1>>24;
        f[8]=w2; f[9]=w2>>8; f[10]=w2>>16; f[11]=w2>>24;
        #pragma unroll
        for (int k = 0; k < 4; ++k)
            am[k] = (f[k*3+0]?1u:0u) | (f[k*3+1]?2u:0u) | (f[k*3+2]?4u:0u);
    } else {
        const int4* i4 = (const int4*)(altI + (size_t)a0 * 3);          // 48 B
        int4 w0 = i4[0], w1 = i4[1], w2 = i4[2];
        int f[12] = {w0.x,w0.y,w0.z,w0.w, w1.x,w1.y,w1.z,w1.w,
                     w2.x,w2.y,w2.z,w2.w};
        #pragma unroll
        for (int k = 0; k < 4; ++k)
            am[k] = (f[k*3+0]?1u:0u) | (f[k*3+1]?2u:0u) | (f[k*3+2]?4u:0u);
    }

    uint4 pw;
    unsigned* pwp = (unsigned*)&pw;
    #pragma unroll
    for (int k = 0; k < 4; ++k) {
        const bool valid = (an[k] != PADV);
        const bool bb    = ((unsigned)an[k] <= 3u);   // BACKBONE = {0,1,2,3}
        const int  r     = (bi[k] * NCHAIN + ch[k]) * SEQL + rn[k];
        const bool rOK   = ((unsigned)r < (unsigned)NRESID);
        const unsigned a = (valid && rOK) ? am[k] : 0u;
        const unsigned res = (unsigned)(rs[k] & 31);
        pwp[k] = (rOK ? (unsigned)r : 0u) | (res << 14)
               | ((bb ? 1u : 0u) << 19) | (a << 20);
        if (bb && a) {                                // idempotent seq stores
            if (a & 1) seq[r * 3 + 0] = rs[k] & 31;
            if (a & 2) seq[r * 3 + 1] = rs[k] & 31;
            if (a & 4) seq[r * 3 + 2] = rs[k] & 31;
        }
    }
    *(uint4*)(pack + a0) = pw;
}

// ---------------------------------------------------------------------------
// scan: block = (chunk c = blockIdx%8, slice s = blockIdx/8).
// LDS: 6 planes x 2048 residues = 48 KB. part layout: [S][6][NRESID].
// ---------------------------------------------------------------------------
__global__ __launch_bounds__(1024)
void k_scan(const float* __restrict__ contRat,       // [NATOMS][NALT]
            const unsigned* __restrict__ pack,
            float* __restrict__ part,
            int S, int sliceSz) {
    __shared__ float acc[6 * CHSZ];                  // 48 KB

    const int c = blockIdx.x & (NCHUNK - 1);
    const int s = blockIdx.x >> 3;

    for (int j = threadIdx.x; j < 6 * CHSZ; j += blockDim.x) acc[j] = 0.0f;
    __syncthreads();

    const int start = s * sliceSz;
    int end = start + sliceSz;
    if (end > NATOMS) end = NATOMS;

    int i = start + (int)threadIdx.x * 4;
    const int step = (int)blockDim.x * 4;

    #define PROCESS(w, idx)                                                   \
        do {                                                                  \
            const unsigned am_ = PK_AM(w);                                    \
            if (am_) {                                                        \
                const int r_ = PK_R(w);                                       \
                if ((r_ >> 11) == c) {                                        \
                    const int lr_ = r_ & (CHSZ - 1);                          \
                    const int pb_ = (PK_BB(w) ? 0 : 3) * CHSZ + lr_;          \
                    const float* cr_ = contRat + (size_t)(idx) * 3;           \
                    if (am_ & 1) atomicAdd(&acc[pb_ + 0 * CHSZ], cr_[0]);     \
                    if (am_ & 2) atomicAdd(&acc[pb_ + 1 * CHSZ], cr_[1]);     \
                    if (am_ & 4) atomicAdd(&acc[pb_ + 2 * CHSZ], cr_[2]);     \
                }                                                             \
            }                                                                 \
        } while (0)

    for (; i + 3 < end; i += step) {
        const uint4 w4 = *(const uint4*)(pack + i);
        PROCESS(w4.x, i);
        PROCESS(w4.y, i + 1);
        PROCESS(w4.z, i + 2);
        PROCESS(w4.w, i + 3);
    }
    for (int k = i; k < end && k < i + 4; ++k) PROCESS(pack[k], k);
    #undef PROCESS

    __syncthreads();

    // flush: part[s][plane][c*CHSZ + j]
    for (int t = threadIdx.x; t < 6 * CHSZ; t += blockDim.x) {
        const int plane = t >> 11;
        const int j     = t & (CHSZ - 1);
        part[((size_t)s * 6 + plane) * NRESID + c * CHSZ + j] = acc[t];
    }
}

// ---------------------------------------------------------------------------
// reduce partials + normalize + clip -> d_out. plane MC = alt, SC = 3+alt.
// seq < 0 (incl. 0xAA poison) => no residue. No init kernel needed: for
// untouched bins sum==0 and min>=0, so normalize goes negative -> clips to 0
// either way.
// ---------------------------------------------------------------------------
__global__ void k_reduce(const float* __restrict__ part, int S,
                         const int* __restrict__ seq,
                         float* __restrict__ out,      // [2*NBINS]
                         const float* __restrict__ mcmax,
                         const float* __restrict__ mcmin,
                         const float* __restrict__ scmax,
                         const float* __restrict__ scmin) {
    int t = blockIdx.x * blockDim.x + threadIdx.x;
    if (t >= NBINS) return;
    const int r   = t & (NRESID - 1);
    const int alt = t >> 14;

    float m = 0.0f, v = 0.0f;
    for (int s2 = 0; s2 < S; ++s2) {
        m += part[((size_t)s2 * 6 + alt) * NRESID + r];
        v += part[((size_t)s2 * 6 + 3 + alt) * NRESID + r];
    }

    const int f  = r * NALT + alt;
    const int sq = seq[f];
    if (sq >= 0) {
        int idx = (sq > NRES - 1) ? (NRES - 1) : sq;
        m = (m - mcmin[idx]) / (mcmax[idx] - mcmin[idx]);
        if (sq != GLY) v = (v - scmin[idx]) / (scmax[idx] - scmin[idx]);
        else           v = 0.0f;
    }
    out[f]         = fminf(fmaxf(m, 0.0f), 1.0f);
    out[NBINS + f] = fminf(fmaxf(v, 0.0f), 1.0f);
}

// ---------------------------------------------------------------------------
// Fallback (tiny ws): flat agent-scope atomics (proven R1).
// ---------------------------------------------------------------------------
__global__ void k_init_flat(float* __restrict__ out, int* __restrict__ seq,
                            int* __restrict__ flag,
                            const unsigned char* __restrict__ altBytes) {
    int i = blockIdx.x * blockDim.x + threadIdx.x;
    if (i < NBINS) { out[i] = 0.0f; out[NBINS + i] = 0.0f; seq[i] = PADV; }
    if (blockIdx.x == 0 && threadIdx.x < 64) {
        unsigned char b = altBytes[threadIdx.x * 4 + 1];
        unsigned long long m = __ballot(b != 0);
        if (threadIdx.x == 0) *flag = (m != 0ULL) ? 1 : 0;
    }
}

__global__ void k_scatter_flat(const float* __restrict__ contRat,
                               const int* __restrict__ desc,
                               const unsigned char* __restrict__ altB,
                               const int* __restrict__ altI,
                               const int* __restrict__ flag,
                               float* __restrict__ mcArr,
                               float* __restrict__ scArr,
                               int* __restrict__ seq) {
    int a = blockIdx.x * blockDim.x + threadIdx.x;
    if (a >= NATOMS) return;
    const int atname  = desc[a * 5 + 0];
    const int resnum  = desc[a * 5 + 1];
    const int chain   = desc[a * 5 + 2];
    const int batchI  = desc[a * 5 + 3];
    const int resname = desc[a * 5 + 4];
    const bool valid = (atname != PADV);
    const bool is_bb = (atname >= 0) && (atname <= 3);
    const int  base  = ((batchI * NCHAIN + chain) * SEQL + resnum) * NALT;
    const bool byteLayout = (*flag != 0);
    #pragma unroll
    for (int alt = 0; alt < NALT; ++alt) {
        bool altv;
        if (byteLayout) altv = (altB[a * NALT + alt] != 0);
        else            altv = (altI[a * NALT + alt] != 0);
        if (altv && valid) {
            const float c = contRat[a * NALT + alt];
            const int   f = base + alt;
            if (is_bb) { atomicAdd(&mcArr[f], c); seq[f] = resname; }
            else       { atomicAdd(&scArr[f], c); }
        }
    }
}

__global__ void k_final_flat(float* __restrict__ mc, float* __restrict__ sc,
                             const int* __restrict__ seq,
                             const float* __restrict__ mcmax,
                             const float* __restrict__ mcmin,
                             const float* __restrict__ scmax,
                             const float* __restrict__ scmin) {
    int i = blockIdx.x * blockDim.x + threadIdx.x;
    if (i >= NBINS) return;
    const int s = seq[i];
    float m = mc[i], v = sc[i];
    if (s != PADV) {
        int idx = s < 0 ? 0 : (s > NRES - 1 ? NRES - 1 : s);
        m = (m - mcmin[idx]) / (mcmax[idx] - mcmin[idx]);
        if (s != GLY) v = (v - scmin[idx]) / (scmax[idx] - scmin[idx]);
        else          v = 0.0f;
    }
    mc[i] = fminf(fmaxf(m, 0.0f), 1.0f);
    sc[i] = fminf(fmaxf(v, 0.0f), 1.0f);
}

// ---------------------------------------------------------------------------
extern "C" void kernel_launch(void* const* d_in, const int* in_sizes, int n_in,
                              void* d_out, int out_size, void* d_ws, size_t ws_size,
                              hipStream_t stream) {
    const float* contRat = (const float*)d_in[0];
    const float* mcmax   = (const float*)d_in[1];
    const float* mcmin   = (const float*)d_in[2];
    const float* scmax   = (const float*)d_in[3];
    const float* scmin   = (const float*)d_in[4];
    const int*   desc    = (const int*)d_in[5];
    const void*  alts    = d_in[6];

    float* out = (float*)d_out;

    const size_t packBytes  = (size_t)NATOMS * sizeof(unsigned);   // 8 MB
    const size_t seqBytes   = (size_t)NBINS * sizeof(int);         // 192 KB
    const size_t sliceBytes = (size_t)6 * NRESID * sizeof(float);  // 384 KB

    int S = 0;
    if (ws_size > packBytes + seqBytes + 64) {
        size_t s = (ws_size - packBytes - seqBytes - 64) / sliceBytes;
        S = (s > SMAXSL) ? SMAXSL : (int)s;
    }

    const int binBlocks = (NBINS + 255) / 256;

    if (S >= 2) {
        unsigned* pack = (unsigned*)d_ws;
        float*    part = (float*)((char*)d_ws + packBytes);
        int*      seq  = (int*)((char*)d_ws + packBytes + (size_t)S * sliceBytes);

        int sliceSz = (NATOMS + S - 1) / S;
        sliceSz = (sliceSz + 3) & ~3;                 // keep uint4 alignment

        k_pack<<<(NATOMS / 4 + 255) / 256, 256, 0, stream>>>(
            desc, (const unsigned char*)alts, (const int*)alts, pack, seq);
        k_scan<<<NCHUNK * S, 1024, 0, stream>>>(contRat, pack, part, S, sliceSz);
        k_reduce<<<binBlocks, 256, 0, stream>>>(
            part, S, seq, out, mcmax, mcmin, scmax, scmin);
    } else {
        // ws too small: flat agent-scope atomic path
        int* seq  = (int*)d_ws;
        int* flag = seq + NBINS;
        k_init_flat<<<binBlocks, 256, 0, stream>>>(out, seq, flag,
                                                   (const unsigned char*)alts);
        k_scatter_flat<<<(NATOMS + 255) / 256, 256, 0, stream>>>(
            contRat, desc,
            (const unsigned char*)alts, (const int*)alts, flag,
            out, out + NBINS, seq);
        k_final_flat<<<binBlocks, 256, 0, stream>>>(
            out, out + NBINS, seq, mcmax, mcmin, scmax, scmin);
    }
}